// Round 5
// baseline (2985.776 us; speedup 1.0000x reference)
//
#include <hip/hip_runtime.h>
#include <math.h>

#pragma clang fp contract(off)

#define RR 7
#define HH 2048
#define WW 2048
#define PH 2062
#define PW 2062
#define PITCH 2080
#define PLANE (PITCH * PH)

#define BLK 256
#define WOUT 496        // output cols per block (threads 0..247, 2 cols each)
#define TYB 32          // output rows per block (multiple of 16)
#define GX 5            // 5*496 = 2480 >= 2062
#define GY 65           // 65*32 = 2080 >= 2062

__global__ __launch_bounds__(256) void sw_pad(const float* __restrict__ img,
                                              float* __restrict__ dst) {
    int idx = blockIdx.x * blockDim.x + threadIdx.x;
    if (idx >= PW * PH) return;
    int y = idx / PW, x = idx - y * PW;
    int sy = y - RR; sy = sy < 0 ? 0 : (sy > HH - 1 ? HH - 1 : sy);
    int sx = x - RR; sx = sx < 0 ? 0 : (sx > WW - 1 ? WW - 1 : sx);
    const float* p = img + ((long)sy * WW + sx) * 3;
    long o = (long)y * PITCH + x;
    dst[o] = p[0];
    dst[(long)PLANE + o] = p[1];
    dst[2L * PLANE + o] = p[2];
}

__global__ __launch_bounds__(256) void sw_crop(const float* __restrict__ src,
                                               float* __restrict__ out) {
    int idx = blockIdx.x * blockDim.x + threadIdx.x;
    if (idx >= HH * WW) return;
    int y = idx / WW, x = idx - y * WW;
    long o = (long)(y + RR) * PITCH + (x + RR);
    out[(long)idx * 3 + 0] = src[o];
    out[(long)idx * 3 + 1] = src[(long)PLANE + o];
    out[(long)idx * 3 + 2] = src[2L * PLANE + o];
}

// Streaming tap update for one pixel. i = tap index 0..14 (compile-time).
// Chains identical to R4: hL8 = taps 0..7, hR8 = taps 7..14, hF15 = taps 0..14,
// sequential ascending, mul-then-add, contract off.
#define PX_TAP(q, i, aLx, aLy, aLz, aRx, aRy, aRz, fx, fy, xc)                          \
    do {                                                                                \
        if ((i) == 0) {                                                                 \
            aLx = 0.125f * (q).x; aLy = 0.125f * (q).y; aLz = 0.125f * (q).z;           \
            fx = c15 * (q).x; fy = c15 * (q).y;                                         \
        } else {                                                                        \
            if ((i) <= 7) {                                                             \
                aLx = aLx + 0.125f * (q).x; aLy = aLy + 0.125f * (q).y;                 \
                aLz = aLz + 0.125f * (q).z;                                             \
            }                                                                           \
            if ((i) == 7) {                                                             \
                aRx = 0.125f * (q).x; aRy = 0.125f * (q).y; aRz = 0.125f * (q).z;       \
                xc = (q).w;                                                             \
            }                                                                           \
            if ((i) > 7 && (i) <= 14) {                                                 \
                aRx = aRx + 0.125f * (q).x; aRy = aRy + 0.125f * (q).y;                 \
                aRz = aRz + 0.125f * (q).z;                                             \
            }                                                                           \
            if ((i) <= 14) { fx = fx + c15 * (q).x; fy = fy + c15 * (q).y; }            \
        }                                                                               \
    } while (0)

__global__ __launch_bounds__(BLK, 4) void sw_iter(const float* __restrict__ src,
                                                  float* __restrict__ dst) {
    // [chunk-row 0..3][half 0..1][col-idx 0..255], float4 {o1L,o1R,o1F,x}: 32 KB
    __shared__ float4 lds4[4 * 512];
    const int tid = threadIdx.x;
    const int x0 = blockIdx.x * WOUT;
    const int y0 = blockIdx.y * TYB;          // multiple of 16
    const int z = blockIdx.z;
    const float* sp = src + (long)z * PLANE;
    float* dp = dst + (long)z * PLANE;

    const int gc0 = x0 - 8 + 2 * tid;         // this thread's even staged col
    const bool gok = (gc0 >= 0) && (gc0 < PW);   // gc0 even, PW even -> pair mask
    const int oc0 = x0 + 2 * tid;             // this thread's even output col
    const bool comp = (tid < WOUT / 2) && (oc0 < PW);

    const float c15 = 1.0f / 15.0f;

    // register rings: input rows (slot = row & 15) for the 2 staged cols
    float xa[16], xb[16];
#pragma unroll
    for (int i = 0; i < 16; ++i) { xa[i] = 0.0f; xb[i] = 0.0f; }

    // warm-up: load rows y0-7 .. y0+6 (no vertical compute)
#pragma unroll
    for (int k = 0; k < 14; ++k) {
        const int r = y0 - 7 + k;
        float2 v = make_float2(0.0f, 0.0f);
        if (gok && r >= 0) v = *(const float2*)(sp + (long)r * PITCH + gc0);
        xa[(k + 9) & 15] = v.x;
        xb[(k + 9) & 15] = v.y;
    }

    for (int cc = 0; cc < 2; ++cc) {
        const int jb16 = 16 * cc;
#pragma unroll
        for (int c4 = 0; c4 < 4; ++c4) {
            __syncthreads();   // previous horizontal pass done with LDS rows
            // ---- vertical stage: o1 rows m = y0+jb16+4*c4+s ----
#pragma unroll
            for (int s = 0; s < 4; ++s) {
                const int jm = 4 * c4 + s;            // row offset mod 16
                const int t = y0 + jb16 + jm + 7;     // newest input row
                float2 v = make_float2(0.0f, 0.0f);
                if (gok && t < PH) v = *(const float2*)(sp + (long)t * PITCH + gc0);
                xa[(jm + 7) & 15] = v.x;
                xb[(jm + 7) & 15] = v.y;

                // vertical chains, taps k = rows m-7+k, slot (jm+9+k)&15
                float aL0 = 0.125f * xa[(jm + 9) & 15];
                float aL1 = 0.125f * xb[(jm + 9) & 15];
#pragma unroll
                for (int k = 1; k < 8; ++k) {
                    aL0 = aL0 + 0.125f * xa[(jm + 9 + k) & 15];
                    aL1 = aL1 + 0.125f * xb[(jm + 9 + k) & 15];
                }
                float aR0 = 0.125f * xa[jm & 15];     // tap k=7 = row m
                float aR1 = 0.125f * xb[jm & 15];
#pragma unroll
                for (int k = 8; k < 15; ++k) {
                    aR0 = aR0 + 0.125f * xa[(jm + 9 + k) & 15];
                    aR1 = aR1 + 0.125f * xb[(jm + 9 + k) & 15];
                }
                float aF0 = c15 * xa[(jm + 9) & 15];
                float aF1 = c15 * xb[(jm + 9) & 15];
#pragma unroll
                for (int k = 1; k < 15; ++k) {
                    aF0 = aF0 + c15 * xa[(jm + 9 + k) & 15];
                    aF1 = aF1 + c15 * xb[(jm + 9 + k) & 15];
                }
                const float X0 = xa[jm & 15];
                const float X1 = xb[jm & 15];
                lds4[s * 512 + tid]       = make_float4(aL0, aR0, aF0, X0); // even col
                lds4[s * 512 + 256 + tid] = make_float4(aL1, aR1, aF1, X1); // odd col
            }
            __syncthreads();
            // ---- horizontal stage ----
            if (comp) {
#pragma unroll 1
                for (int s = 0; s < 4; ++s) {
                    const int m = y0 + jb16 + 4 * c4 + s;
                    if (m >= PH) break;
                    const float4* rowb = lds4 + s * 512;
                    const float4* Eb = rowb + tid + 1;        // even cols 2t+2+2k
                    const float4* Ob = rowb + 256 + tid;      // odd cols 2t+1+2k

                    float a0Lx, a0Ly, a0Lz, a0Rx, a0Ry, a0Rz, f0x, f0y, xc0;
                    float a1Lx, a1Ly, a1Lz, a1Rx, a1Ry, a1Rz, f1x, f1y, xc1;
                    // stream 16 taps: seq[j] = cols oc0-7 .. oc0+8 ascending
#pragma unroll
                    for (int j = 0; j < 16; ++j) {
                        float4 q = (j & 1) ? Eb[(j - 1) >> 1] : Ob[j >> 1];
                        if (j <= 14) PX_TAP(q, j, a0Lx, a0Ly, a0Lz, a0Rx, a0Ry, a0Rz, f0x, f0y, xc0);
                        if (j >= 1)  PX_TAP(q, (j - 1), a1Lx, a1Ly, a1Lz, a1Rx, a1Ry, a1Rz, f1x, f1y, xc1);
                    }

                    float d0 = a0Lx - xc0, d1 = a0Rx - xc0;
                    float d2 = a0Ly - xc0, d3 = a0Ry - xc0;
                    float d4 = f0x - xc0,  d5 = f0y - xc0;
                    float d6 = a0Lz - xc0, d7 = a0Rz - xc0;
                    float best = d0, ba = fabsf(d0), a;
                    a = fabsf(d1); if (a < ba) { ba = a; best = d1; }
                    a = fabsf(d2); if (a < ba) { ba = a; best = d2; }
                    a = fabsf(d3); if (a < ba) { ba = a; best = d3; }
                    a = fabsf(d4); if (a < ba) { ba = a; best = d4; }
                    a = fabsf(d5); if (a < ba) { ba = a; best = d5; }
                    a = fabsf(d6); if (a < ba) { ba = a; best = d6; }
                    a = fabsf(d7); if (a < ba) { ba = a; best = d7; }
                    float out0 = xc0 + best;

                    d0 = a1Lx - xc1; d1 = a1Rx - xc1;
                    d2 = a1Ly - xc1; d3 = a1Ry - xc1;
                    d4 = f1x - xc1;  d5 = f1y - xc1;
                    d6 = a1Lz - xc1; d7 = a1Rz - xc1;
                    best = d0; ba = fabsf(d0);
                    a = fabsf(d1); if (a < ba) { ba = a; best = d1; }
                    a = fabsf(d2); if (a < ba) { ba = a; best = d2; }
                    a = fabsf(d3); if (a < ba) { ba = a; best = d3; }
                    a = fabsf(d4); if (a < ba) { ba = a; best = d4; }
                    a = fabsf(d5); if (a < ba) { ba = a; best = d5; }
                    a = fabsf(d6); if (a < ba) { ba = a; best = d6; }
                    a = fabsf(d7); if (a < ba) { ba = a; best = d7; }
                    float out1 = xc1 + best;

                    *(float2*)(dp + (long)m * PITCH + oc0) = make_float2(out0, out1);
                }
            }
        }
    }
}

extern "C" void kernel_launch(void* const* d_in, const int* in_sizes, int n_in,
                              void* d_out, int out_size, void* d_ws, size_t ws_size,
                              hipStream_t stream) {
    (void)in_sizes; (void)n_in; (void)out_size; (void)ws_size;
    const float* img = (const float*)d_in[0];
    float* out = (float*)d_out;
    float* A = (float*)d_ws;
    float* B = A + 3L * PLANE;

    {
        int total = PW * PH;
        int g = (total + 255) / 256;
        sw_pad<<<dim3(g), dim3(256), 0, stream>>>(img, A);
    }
    dim3 grid(GX, GY, 3), block(BLK);
    for (int i = 0; i < 10; ++i) {
        const float* s = (i & 1) ? B : A;
        float* d = (i & 1) ? A : B;
        sw_iter<<<grid, block, 0, stream>>>(s, d);
    }
    // iter 9 (odd) writes A: final state in A.
    {
        int total = HH * WW;
        int g = (total + 255) / 256;
        sw_crop<<<dim3(g), dim3(256), 0, stream>>>(A, out);
    }
}

// Round 6
// 1326.209 us; speedup vs baseline: 2.2514x; 2.2514x over previous
//
#include <hip/hip_runtime.h>
#include <math.h>

#pragma clang fp contract(off)

#define RR 7
#define HH 2048
#define WW 2048
#define PH 2062
#define PW 2062
#define PITCH 2080
#define PLANE (PITCH * PH)

#define BLK 128
#define NQ 124          // output quads per block (threads 0..123)
#define WOUT 496        // 124*4 output cols per block
#define TYB 32          // output rows per block
#define GX 5            // 5*496 = 2480 >= 2062
#define GY 65           // 65*32 = 2080 >= 2062

__global__ __launch_bounds__(256) void sw_pad(const float* __restrict__ img,
                                              float* __restrict__ dst) {
    int idx = blockIdx.x * blockDim.x + threadIdx.x;
    if (idx >= PW * PH) return;
    int y = idx / PW, x = idx - y * PW;
    int sy = y - RR; sy = sy < 0 ? 0 : (sy > HH - 1 ? HH - 1 : sy);
    int sx = x - RR; sx = sx < 0 ? 0 : (sx > WW - 1 ? WW - 1 : sx);
    const float* p = img + ((long)sy * WW + sx) * 3;
    long o = (long)y * PITCH + x;
    dst[o] = p[0];
    dst[(long)PLANE + o] = p[1];
    dst[2L * PLANE + o] = p[2];
}

__global__ __launch_bounds__(256) void sw_crop(const float* __restrict__ src,
                                               float* __restrict__ out) {
    int idx = blockIdx.x * blockDim.x + threadIdx.x;
    if (idx >= HH * WW) return;
    int y = idx / WW, x = idx - y * WW;
    long o = (long)(y + RR) * PITCH + (x + RR);
    out[(long)idx * 3 + 0] = src[o];
    out[(long)idx * 3 + 1] = src[(long)PLANE + o];
    out[(long)idx * 3 + 2] = src[2L * PLANE + o];
}

__global__ __launch_bounds__(BLK) void sw_iter(const float* __restrict__ src,
                                               float* __restrict__ dst) {
    // raw input ring: [slot 0..15][tid] -> thread's 4 staged cols (32 KB).
    // Each thread only ever touches its own column quad -> no barriers needed.
    __shared__ float4 rawW[16][BLK];
    // one row of vertical-stage output, per staged col: {o1L,o1R,o1F,x} (8 KB)
    __shared__ float4 o1row[4 * BLK];

    const int tid = threadIdx.x;
    const int x0 = blockIdx.x * WOUT;
    const int y0 = blockIdx.y * TYB;
    const int z  = blockIdx.z;
    const float* sp = src + (long)z * PLANE;
    float* dp = dst + (long)z * PLANE;

    const int sc0 = x0 - 8 + 4 * tid;              // first staged col
    const bool fullin = (sc0 >= 0) && (sc0 + 3 < PW);
    const bool anyin  = (sc0 + 3 >= 0) && (sc0 < PW);
    const int oc0 = x0 + 4 * tid;                  // first output col
    const bool hout = (tid < NQ) && (oc0 < PW);

    const float c15 = 1.0f / 15.0f;

    auto loadrow = [&](int t) -> float4 {
        float4 v = make_float4(0.f, 0.f, 0.f, 0.f);
        if (t >= 0 && t < PH) {
            if (fullin) {
                v = *(const float4*)(sp + (long)t * PITCH + sc0);
            } else if (anyin) {
                const float* rp = sp + (long)t * PITCH;
                if (sc0 >= 0 && sc0 < PW)         v.x = rp[sc0];
                if (sc0 + 1 >= 0 && sc0 + 1 < PW) v.y = rp[sc0 + 1];
                if (sc0 + 2 >= 0 && sc0 + 2 < PW) v.z = rp[sc0 + 2];
                if (sc0 + 3 >= 0 && sc0 + 3 < PW) v.w = rp[sc0 + 3];
            }
        }
        return v;
    };

    // warm-up: rows y0-7 .. y0+6 into the ring (zero-pad outside)
#pragma unroll 1
    for (int k = 0; k < 14; ++k) {
        const int r = y0 - 7 + k;
        rawW[r & 15][tid] = loadrow(r);
    }
    float4 vld = loadrow(y0 + 7);                  // prefetched row m+7

#pragma unroll 1
    for (int s = 0; s < TYB; ++s) {
        const int m = y0 + s;                      // output row (uniform)
        if (m >= PH) break;
        rawW[(m + 7) & 15][tid] = vld;
        const float4 vtop = vld;                   // row m+7 (vertical tap k=14)
        vld = loadrow(m + 8);                      // prefetch next step

        // ---- vertical stage: rows m-7..m+7, ascending, mul-then-add ----
        float aL[4], aR[4], aF[4], xq[4];
        {
            float4 q = rawW[(m - 7) & 15][tid];    // k = 0
            float qq[4] = {q.x, q.y, q.z, q.w};
#pragma unroll
            for (int cix = 0; cix < 4; ++cix) {
                aL[cix] = 0.125f * qq[cix];
                aF[cix] = c15 * qq[cix];
            }
        }
#pragma unroll
        for (int k = 1; k <= 14; ++k) {
            float4 q = (k == 14) ? vtop : rawW[(m - 7 + k) & 15][tid];
            float qq[4] = {q.x, q.y, q.z, q.w};
#pragma unroll
            for (int cix = 0; cix < 4; ++cix) {
                if (k <= 7)  aL[cix] = aL[cix] + 0.125f * qq[cix];
                if (k == 7)  { aR[cix] = 0.125f * qq[cix]; xq[cix] = qq[cix]; }
                if (k >= 8)  aR[cix] = aR[cix] + 0.125f * qq[cix];
                aF[cix] = aF[cix] + c15 * qq[cix];
            }
        }
#pragma unroll
        for (int cix = 0; cix < 4; ++cix)
            o1row[4 * tid + cix] = make_float4(aL[cix], aR[cix], aF[cix], xq[cix]);
        __syncthreads();

        // ---- horizontal stage: 18-tap stream feeding 4 pixels ----
        if (hout) {
            float hLL[4], hRL[4], hLR[4], hRR[4], hFL[4], hFR[4], hLF[4], hRF[4], xc[4];
            const float4* tap = o1row + 4 * tid + 1;
#pragma unroll
            for (int j = 0; j < 18; ++j) {
                float4 q = tap[j];
#pragma unroll
                for (int i = 0; i < 4; ++i) {
                    const int ti = j - i;          // tap index for pixel i
                    if (ti < 0 || ti > 14) continue;
                    if (ti == 0) {
                        hLL[i] = 0.125f * q.x; hLR[i] = 0.125f * q.y; hLF[i] = 0.125f * q.z;
                        hFL[i] = c15 * q.x;    hFR[i] = c15 * q.y;
                    } else if (ti <= 7) {
                        hLL[i] = hLL[i] + 0.125f * q.x;
                        hLR[i] = hLR[i] + 0.125f * q.y;
                        hLF[i] = hLF[i] + 0.125f * q.z;
                        hFL[i] = hFL[i] + c15 * q.x;
                        hFR[i] = hFR[i] + c15 * q.y;
                        if (ti == 7) {
                            hRL[i] = 0.125f * q.x; hRR[i] = 0.125f * q.y;
                            hRF[i] = 0.125f * q.z; xc[i] = q.w;
                        }
                    } else {
                        hRL[i] = hRL[i] + 0.125f * q.x;
                        hRR[i] = hRR[i] + 0.125f * q.y;
                        hRF[i] = hRF[i] + 0.125f * q.z;
                        hFL[i] = hFL[i] + c15 * q.x;
                        hFR[i] = hFR[i] + c15 * q.y;
                    }
                }
            }

            float res[4];
#pragma unroll
            for (int i = 0; i < 4; ++i) {
                float d0 = hLL[i] - xc[i], d1 = hRL[i] - xc[i];
                float d2 = hLR[i] - xc[i], d3 = hRR[i] - xc[i];
                float d4 = hFL[i] - xc[i], d5 = hFR[i] - xc[i];
                float d6 = hLF[i] - xc[i], d7 = hRF[i] - xc[i];
                float best = d0, ba = fabsf(d0), a;
                a = fabsf(d1); if (a < ba) { ba = a; best = d1; }
                a = fabsf(d2); if (a < ba) { ba = a; best = d2; }
                a = fabsf(d3); if (a < ba) { ba = a; best = d3; }
                a = fabsf(d4); if (a < ba) { ba = a; best = d4; }
                a = fabsf(d5); if (a < ba) { ba = a; best = d5; }
                a = fabsf(d6); if (a < ba) { ba = a; best = d6; }
                a = fabsf(d7); if (a < ba) { ba = a; best = d7; }
                res[i] = xc[i] + best;
            }
            float* orow = dp + (long)m * PITCH + oc0;
            if (oc0 + 3 < PW) {
                *(float4*)orow = make_float4(res[0], res[1], res[2], res[3]);
            } else {
                if (oc0 < PW)     orow[0] = res[0];
                if (oc0 + 1 < PW) orow[1] = res[1];
                if (oc0 + 2 < PW) orow[2] = res[2];
            }
        }
        __syncthreads();
    }
}

extern "C" void kernel_launch(void* const* d_in, const int* in_sizes, int n_in,
                              void* d_out, int out_size, void* d_ws, size_t ws_size,
                              hipStream_t stream) {
    (void)in_sizes; (void)n_in; (void)out_size; (void)ws_size;
    const float* img = (const float*)d_in[0];
    float* out = (float*)d_out;
    float* A = (float*)d_ws;
    float* B = A + 3L * PLANE;

    {
        int total = PW * PH;
        int g = (total + 255) / 256;
        sw_pad<<<dim3(g), dim3(256), 0, stream>>>(img, A);
    }
    dim3 grid(GX, GY, 3), block(BLK);
    for (int i = 0; i < 10; ++i) {
        const float* s = (i & 1) ? B : A;
        float* d = (i & 1) ? A : B;
        sw_iter<<<grid, block, 0, stream>>>(s, d);
    }
    // iter 9 (odd) writes A: final state in A.
    {
        int total = HH * WW;
        int g = (total + 255) / 256;
        sw_crop<<<dim3(g), dim3(256), 0, stream>>>(A, out);
    }
}

// Round 7
// 1139.348 us; speedup vs baseline: 2.6206x; 1.1640x over previous
//
#include <hip/hip_runtime.h>
#include <math.h>

#pragma clang fp contract(off)

#define RR 7
#define HH 2048
#define WW 2048
#define PH 2062
#define PW 2062
#define PITCH 2080
#define PLANE (PITCH * PH)

#define BLK 256
#define WOUT 496        // output cols per block (threads 0..247, 2 cols each)
#define TYB 32          // output rows per block (multiple of 16)
#define GX 5            // 5*496 = 2480 >= 2062
#define GY 65           // 65*32 = 2080 >= 2062

__global__ __launch_bounds__(256) void sw_pad(const float* __restrict__ img,
                                              float* __restrict__ dst) {
    int idx = blockIdx.x * blockDim.x + threadIdx.x;
    if (idx >= PW * PH) return;
    int y = idx / PW, x = idx - y * PW;
    int sy = y - RR; sy = sy < 0 ? 0 : (sy > HH - 1 ? HH - 1 : sy);
    int sx = x - RR; sx = sx < 0 ? 0 : (sx > WW - 1 ? WW - 1 : sx);
    const float* p = img + ((long)sy * WW + sx) * 3;
    long o = (long)y * PITCH + x;
    dst[o] = p[0];
    dst[(long)PLANE + o] = p[1];
    dst[2L * PLANE + o] = p[2];
}

__global__ __launch_bounds__(256) void sw_crop(const float* __restrict__ src,
                                               float* __restrict__ out) {
    int idx = blockIdx.x * blockDim.x + threadIdx.x;
    if (idx >= HH * WW) return;
    int y = idx / WW, x = idx - y * WW;
    long o = (long)(y + RR) * PITCH + (x + RR);
    out[(long)idx * 3 + 0] = src[o];
    out[(long)idx * 3 + 1] = src[(long)PLANE + o];
    out[(long)idx * 3 + 2] = src[2L * PLANE + o];
}

// Streaming tap update for one pixel. i = tap index 0..14 (compile-time).
// Chains identical to R4: hL8 = taps 0..7, hR8 = taps 7..14, hF15 = taps 0..14,
// sequential ascending, mul-then-add, contract off.
#define PX_TAP(q, i, aLx, aLy, aLz, aRx, aRy, aRz, fx, fy, xc)                          \
    do {                                                                                \
        if ((i) == 0) {                                                                 \
            aLx = 0.125f * (q).x; aLy = 0.125f * (q).y; aLz = 0.125f * (q).z;           \
            fx = c15 * (q).x; fy = c15 * (q).y;                                         \
        } else {                                                                        \
            if ((i) <= 7) {                                                             \
                aLx = aLx + 0.125f * (q).x; aLy = aLy + 0.125f * (q).y;                 \
                aLz = aLz + 0.125f * (q).z;                                             \
            }                                                                           \
            if ((i) == 7) {                                                             \
                aRx = 0.125f * (q).x; aRy = 0.125f * (q).y; aRz = 0.125f * (q).z;       \
                xc = (q).w;                                                             \
            }                                                                           \
            if ((i) > 7 && (i) <= 14) {                                                 \
                aRx = aRx + 0.125f * (q).x; aRy = aRy + 0.125f * (q).y;                 \
                aRz = aRz + 0.125f * (q).z;                                             \
            }                                                                           \
            if ((i) <= 14) { fx = fx + c15 * (q).x; fy = fy + c15 * (q).y; }            \
        }                                                                               \
    } while (0)

__global__ __launch_bounds__(BLK) void sw_iter(const float* __restrict__ src,
                                               float* __restrict__ dst) {
    // [chunk-row 0..3][half 0..1][col-idx 0..255], float4 {o1L,o1R,o1F,x}: 32 KB
    // even/odd phase split -> horizontal taps are 16 B/lane stride (conflict-free)
    __shared__ float4 lds4[4 * 512];
    const int tid = threadIdx.x;
    const int x0 = blockIdx.x * WOUT;
    const int y0 = blockIdx.y * TYB;          // multiple of 16
    const int z = blockIdx.z;
    const float* sp = src + (long)z * PLANE;
    float* dp = dst + (long)z * PLANE;

    const int gc0 = x0 - 8 + 2 * tid;         // this thread's even staged col
    const bool gok = (gc0 >= 0) && (gc0 < PW);   // gc0 even, PW even -> pair mask
    const int oc0 = x0 + 2 * tid;             // this thread's even output col
    const bool comp = (tid < WOUT / 2) && (oc0 < PW);

    const float c15 = 1.0f / 15.0f;

    // register rings: input rows (slot = row & 15) for the 2 staged cols
    float xa[16], xb[16];
#pragma unroll
    for (int i = 0; i < 16; ++i) { xa[i] = 0.0f; xb[i] = 0.0f; }

    // warm-up: load rows y0-7 .. y0+6 (no vertical compute)
#pragma unroll
    for (int k = 0; k < 14; ++k) {
        const int r = y0 - 7 + k;
        float2 v = make_float2(0.0f, 0.0f);
        if (gok && r >= 0) v = *(const float2*)(sp + (long)r * PITCH + gc0);
        xa[(k + 9) & 15] = v.x;
        xb[(k + 9) & 15] = v.y;
    }

    for (int cc = 0; cc < 2; ++cc) {
        const int jb16 = 16 * cc;
#pragma unroll
        for (int c4 = 0; c4 < 4; ++c4) {
            __syncthreads();   // previous horizontal pass done with LDS rows
            // ---- vertical stage: o1 rows m = y0+jb16+4*c4+s ----
#pragma unroll
            for (int s = 0; s < 4; ++s) {
                const int jm = 4 * c4 + s;            // row offset mod 16
                const int t = y0 + jb16 + jm + 7;     // newest input row
                float2 v = make_float2(0.0f, 0.0f);
                if (gok && t < PH) v = *(const float2*)(sp + (long)t * PITCH + gc0);
                xa[(jm + 7) & 15] = v.x;
                xb[(jm + 7) & 15] = v.y;

                // vertical chains, taps k = rows m-7+k, slot (jm+9+k)&15
                float aL0 = 0.125f * xa[(jm + 9) & 15];
                float aL1 = 0.125f * xb[(jm + 9) & 15];
#pragma unroll
                for (int k = 1; k < 8; ++k) {
                    aL0 = aL0 + 0.125f * xa[(jm + 9 + k) & 15];
                    aL1 = aL1 + 0.125f * xb[(jm + 9 + k) & 15];
                }
                float aR0 = 0.125f * xa[jm & 15];     // tap k=7 = row m
                float aR1 = 0.125f * xb[jm & 15];
#pragma unroll
                for (int k = 8; k < 15; ++k) {
                    aR0 = aR0 + 0.125f * xa[(jm + 9 + k) & 15];
                    aR1 = aR1 + 0.125f * xb[(jm + 9 + k) & 15];
                }
                float aF0 = c15 * xa[(jm + 9) & 15];
                float aF1 = c15 * xb[(jm + 9) & 15];
#pragma unroll
                for (int k = 1; k < 15; ++k) {
                    aF0 = aF0 + c15 * xa[(jm + 9 + k) & 15];
                    aF1 = aF1 + c15 * xb[(jm + 9 + k) & 15];
                }
                const float X0 = xa[jm & 15];
                const float X1 = xb[jm & 15];
                lds4[s * 512 + tid]       = make_float4(aL0, aR0, aF0, X0); // even col
                lds4[s * 512 + 256 + tid] = make_float4(aL1, aR1, aF1, X1); // odd col
            }
            __syncthreads();
            // ---- horizontal stage ----
            if (comp) {
#pragma unroll 1
                for (int s = 0; s < 4; ++s) {
                    const int m = y0 + jb16 + 4 * c4 + s;
                    if (m >= PH) break;
                    const float4* rowb = lds4 + s * 512;
                    const float4* Eb = rowb + tid + 1;        // even cols 2t+2+2k
                    const float4* Ob = rowb + 256 + tid;      // odd cols 2t+1+2k

                    float a0Lx, a0Ly, a0Lz, a0Rx, a0Ry, a0Rz, f0x, f0y, xc0;
                    float a1Lx, a1Ly, a1Lz, a1Rx, a1Ry, a1Rz, f1x, f1y, xc1;
                    // stream 16 taps: seq[j] = cols oc0-7 .. oc0+8 ascending
#pragma unroll
                    for (int j = 0; j < 16; ++j) {
                        float4 q = (j & 1) ? Eb[(j - 1) >> 1] : Ob[j >> 1];
                        if (j <= 14) PX_TAP(q, j, a0Lx, a0Ly, a0Lz, a0Rx, a0Ry, a0Rz, f0x, f0y, xc0);
                        if (j >= 1)  PX_TAP(q, (j - 1), a1Lx, a1Ly, a1Lz, a1Rx, a1Ry, a1Rz, f1x, f1y, xc1);
                    }

                    float d0 = a0Lx - xc0, d1 = a0Rx - xc0;
                    float d2 = a0Ly - xc0, d3 = a0Ry - xc0;
                    float d4 = f0x - xc0,  d5 = f0y - xc0;
                    float d6 = a0Lz - xc0, d7 = a0Rz - xc0;
                    float best = d0, ba = fabsf(d0), a;
                    a = fabsf(d1); if (a < ba) { ba = a; best = d1; }
                    a = fabsf(d2); if (a < ba) { ba = a; best = d2; }
                    a = fabsf(d3); if (a < ba) { ba = a; best = d3; }
                    a = fabsf(d4); if (a < ba) { ba = a; best = d4; }
                    a = fabsf(d5); if (a < ba) { ba = a; best = d5; }
                    a = fabsf(d6); if (a < ba) { ba = a; best = d6; }
                    a = fabsf(d7); if (a < ba) { ba = a; best = d7; }
                    float out0 = xc0 + best;

                    d0 = a1Lx - xc1; d1 = a1Rx - xc1;
                    d2 = a1Ly - xc1; d3 = a1Ry - xc1;
                    d4 = f1x - xc1;  d5 = f1y - xc1;
                    d6 = a1Lz - xc1; d7 = a1Rz - xc1;
                    best = d0; ba = fabsf(d0);
                    a = fabsf(d1); if (a < ba) { ba = a; best = d1; }
                    a = fabsf(d2); if (a < ba) { ba = a; best = d2; }
                    a = fabsf(d3); if (a < ba) { ba = a; best = d3; }
                    a = fabsf(d4); if (a < ba) { ba = a; best = d4; }
                    a = fabsf(d5); if (a < ba) { ba = a; best = d5; }
                    a = fabsf(d6); if (a < ba) { ba = a; best = d6; }
                    a = fabsf(d7); if (a < ba) { ba = a; best = d7; }
                    float out1 = xc1 + best;

                    *(float2*)(dp + (long)m * PITCH + oc0) = make_float2(out0, out1);
                }
            }
        }
    }
}

extern "C" void kernel_launch(void* const* d_in, const int* in_sizes, int n_in,
                              void* d_out, int out_size, void* d_ws, size_t ws_size,
                              hipStream_t stream) {
    (void)in_sizes; (void)n_in; (void)out_size; (void)ws_size;
    const float* img = (const float*)d_in[0];
    float* out = (float*)d_out;
    float* A = (float*)d_ws;
    float* B = A + 3L * PLANE;

    {
        int total = PW * PH;
        int g = (total + 255) / 256;
        sw_pad<<<dim3(g), dim3(256), 0, stream>>>(img, A);
    }
    dim3 grid(GX, GY, 3), block(BLK);
    for (int i = 0; i < 10; ++i) {
        const float* s = (i & 1) ? B : A;
        float* d = (i & 1) ? A : B;
        sw_iter<<<grid, block, 0, stream>>>(s, d);
    }
    // iter 9 (odd) writes A: final state in A.
    {
        int total = HH * WW;
        int g = (total + 255) / 256;
        sw_crop<<<dim3(g), dim3(256), 0, stream>>>(A, out);
    }
}